// Round 1
// baseline (521.412 us; speedup 1.0000x reference)
//
#include <hip/hip_runtime.h>
#include <cmath>

// SVC_63737314673237: RBF-kernel SVC decision on MI355X.
// K[n,s] = exp(-g*(|x_n|^2+|sv_s|^2) + 2g*x_n.sv_s); T[n,r,c] = sum_seg a*K;
// 45 pairwise votes -> argmax class (smallest index on tie), output twice (int32).
//
// Round 1: exact fp32 vector-ALU GEMM (no fp32 MFMA on CDNA4). 64x64 tile,
// 4x4 micro-tile, transposed LDS staging (+4 pad keeps ds_read_b128 alignment).
// grid.y = class segment (500 SVs) so T is written race-free per block.

#define GAMMA 0.01f
constexpr int N  = 8192;
constexpr int D  = 256;
constexpr int S  = 5000;
constexpr int C  = 10;
constexpr int NV = 500;
constexpr int R  = 9;   // C-1

// ---------------- norms: one wave (64 lanes) per row, float4 + butterfly ----
__global__ __launch_bounds__(256) void norm_kernel(const float* __restrict__ x,
                                                   const float* __restrict__ sv,
                                                   float* __restrict__ xn,
                                                   float* __restrict__ svn) {
    int gid  = blockIdx.x * blockDim.x + threadIdx.x;
    int wid  = gid >> 6;
    int lane = gid & 63;
    if (wid >= N + S) return;
    const float* row = (wid < N) ? (x + (size_t)wid * D) : (sv + (size_t)(wid - N) * D);
    float4 v = reinterpret_cast<const float4*>(row)[lane];  // 64 lanes * 4 = 256
    float s = v.x * v.x + v.y * v.y + v.z * v.z + v.w * v.w;
#pragma unroll
    for (int off = 32; off > 0; off >>= 1) s += __shfl_xor(s, off, 64);
    if (lane == 0) {
        if (wid < N) xn[wid] = s;
        else         svn[wid - N] = s;
    }
}

// ---------------- fused GEMM + exp + per-class weighted reduce --------------
// block: 256 threads (16 tx * 16 ty). tile: 64 rows x 64 svs, 4x4 per thread.
// blockIdx.x = row tile (128), blockIdx.y = class (10).
__global__ __launch_bounds__(256, 4) void svc_gemm(const float* __restrict__ x,
                                                   const float* __restrict__ sv,
                                                   const float* __restrict__ a,
                                                   const float* __restrict__ xnorm,
                                                   const float* __restrict__ svnorm,
                                                   float* __restrict__ T) {
    constexpr int PAD = 68;                 // 64 + 4: keeps 16B alignment of rows
    __shared__ float xs[32 * PAD];          // [k][n] transposed -> b128 reads
    __shared__ float ss[32 * PAD];          // [k][s] transposed
    __shared__ float a_sh[R * NV];          // this class's dual-coef segment
    __shared__ float tred[64 * R];          // per-row T reduction buffer

    const int tid = threadIdx.x;
    const int n0  = blockIdx.x * 64;
    const int cls = blockIdx.y;
    const int tx  = tid & 15;
    const int ty  = tid >> 4;

    // stage a[., cls*500 .. +500) (coalesced)
    for (int i = tid; i < R * NV; i += 256) {
        int r = i / NV;
        int m = i - r * NV;
        a_sh[i] = a[(size_t)r * S + cls * NV + m];
    }
    for (int i = tid; i < 64 * R; i += 256) tred[i] = 0.f;

    float xn[4];
#pragma unroll
    for (int i = 0; i < 4; ++i) xn[i] = xnorm[n0 + ty * 4 + i];

    float t[4][R];
#pragma unroll
    for (int i = 0; i < 4; ++i)
#pragma unroll
        for (int r = 0; r < R; ++r) t[i][r] = 0.f;

    for (int sc = 0; sc < 8; ++sc) {        // 8 chunks of 64 svs cover 500 (masked)
        float acc[4][4];
#pragma unroll
        for (int i = 0; i < 4; ++i)
#pragma unroll
            for (int j = 0; j < 4; ++j) acc[i][j] = 0.f;

        for (int kt = 0; kt < 8; ++kt) {    // K loop over D=256 in BK=32
            const int k0 = kt * 32;
            __syncthreads();
            // stage both tiles transposed: 512 float4 each, 2 per thread
#pragma unroll
            for (int p = 0; p < 2; ++p) {
                int q   = tid + p * 256;
                int row = q >> 3;           // 0..63
                int kq  = (q & 7) * 4;      // 0,4,..,28
                float4 v = *reinterpret_cast<const float4*>(
                    x + (size_t)(n0 + row) * D + k0 + kq);
                xs[(kq + 0) * PAD + row] = v.x;
                xs[(kq + 1) * PAD + row] = v.y;
                xs[(kq + 2) * PAD + row] = v.z;
                xs[(kq + 3) * PAD + row] = v.w;
                int sg = cls * NV + sc * 64 + row;   // clamp: tail lanes masked later
                if (sg > S - 1) sg = S - 1;
                float4 w = *reinterpret_cast<const float4*>(
                    sv + (size_t)sg * D + k0 + kq);
                ss[(kq + 0) * PAD + row] = w.x;
                ss[(kq + 1) * PAD + row] = w.y;
                ss[(kq + 2) * PAD + row] = w.z;
                ss[(kq + 3) * PAD + row] = w.w;
            }
            __syncthreads();
#pragma unroll
            for (int kk = 0; kk < 32; ++kk) {
                float4 xa = *reinterpret_cast<const float4*>(xs + kk * PAD + ty * 4);
                float4 sa = *reinterpret_cast<const float4*>(ss + kk * PAD + tx * 4);
                float xv[4] = {xa.x, xa.y, xa.z, xa.w};
                float sb[4] = {sa.x, sa.y, sa.z, sa.w};
#pragma unroll
                for (int i = 0; i < 4; ++i)
#pragma unroll
                    for (int j = 0; j < 4; ++j)
                        acc[i][j] = fmaf(xv[i], sb[j], acc[i][j]);
            }
        }

        // epilogue for this sv chunk: exp + weighted accumulate into t[][]
#pragma unroll
        for (int j = 0; j < 4; ++j) {
            int sl = sc * 64 + tx * 4 + j;  // index within class segment
            if (sl < NV) {
                float sn = svnorm[cls * NV + sl];
                float av[R];
#pragma unroll
                for (int r = 0; r < R; ++r) av[r] = a_sh[r * NV + sl];
#pragma unroll
                for (int i = 0; i < 4; ++i) {
                    float kv = expf(fmaf(2.0f * GAMMA, acc[i][j],
                                         -GAMMA * (xn[i] + sn)));
#pragma unroll
                    for (int r = 0; r < R; ++r) t[i][r] = fmaf(av[r], kv, t[i][r]);
                }
            }
        }
    }

    // reduce per-thread partials (16 tx-threads share each row) via LDS atomics
#pragma unroll
    for (int i = 0; i < 4; ++i)
#pragma unroll
        for (int r = 0; r < R; ++r)
            atomicAdd(&tred[(ty * 4 + i) * R + r], t[i][r]);
    __syncthreads();
    for (int i = tid; i < 64 * R; i += 256) {
        int row = i / R;
        int r   = i - row * R;
        T[(size_t)(n0 + row) * 90 + r * 10 + cls] = tred[i];
    }
}

// ---------------- pairwise voting + argmax (tiny) ---------------------------
__global__ __launch_bounds__(256) void vote_kernel(const float* __restrict__ T,
                                                   const float* __restrict__ b,
                                                   int* __restrict__ out) {
    int n = blockIdx.x * blockDim.x + threadIdx.x;
    if (n >= N) return;
    const float* Tn = T + (size_t)n * 90;
    float tv[90];
#pragma unroll
    for (int i = 0; i < 90; ++i) tv[i] = Tn[i];
    int counts[C];
#pragma unroll
    for (int k = 0; k < C; ++k) counts[k] = 0;
    int p = 0;
#pragma unroll
    for (int i = 0; i < C; ++i) {
#pragma unroll
        for (int j = i + 1; j < C; ++j) {
            float c = tv[i * 10 + j] + tv[(j - 1) * 10 + i] + b[p];
            if (c > 0.f) counts[i]++; else counts[j]++;
            ++p;
        }
    }
    int best = 0;
#pragma unroll
    for (int k = 1; k < C; ++k)
        if (counts[k] > counts[best]) best = k;   // strict > : smallest idx on tie
    out[n]     = best;
    out[N + n] = best;
}

extern "C" void kernel_launch(void* const* d_in, const int* in_sizes, int n_in,
                              void* d_out, int out_size, void* d_ws, size_t ws_size,
                              hipStream_t stream) {
    const float* x  = (const float*)d_in[0];   // [8192,256]
    const float* sv = (const float*)d_in[1];   // [5000,256]
    const float* a  = (const float*)d_in[2];   // [9,5000]
    const float* b  = (const float*)d_in[3];   // [45]
    int* out = (int*)d_out;                    // [2*8192] int32

    // workspace layout (floats): xnorm[8192] | svnorm[5000] | T[8192*90]
    float* ws     = (float*)d_ws;              // needs ~2.9 MB
    float* xnorm  = ws;
    float* svnorm = ws + N;
    float* T      = ws + N + S;

    {   // norms: one wave per row, (8192+5000) waves
        int waves  = N + S;
        int blocks = (waves * 64 + 255) / 256;
        norm_kernel<<<blocks, 256, 0, stream>>>(x, sv, xnorm, svnorm);
    }
    {   // fused GEMM/exp/reduce: 128 row tiles x 10 classes
        dim3 grid(N / 64, C);
        svc_gemm<<<grid, 256, 0, stream>>>(x, sv, a, xnorm, svnorm, T);
    }
    {   // voting
        vote_kernel<<<N / 256, 256, 0, stream>>>(T, b, out);
    }
}

// Round 2
// 210.597 us; speedup vs baseline: 2.4759x; 2.4759x over previous
//
#include <hip/hip_runtime.h>
#include <hip/hip_fp16.h>
#include <cmath>

// SVC_63737314673237 round 2: split-precision f16 MFMA GEMM.
// dot(x,sv) = xh.sh + 2^-12*(xh.(4096*sl) + (4096*xl).sh)  -- fp32-grade accuracy,
// runs on the 2 PF matrix pipe instead of the 157 TF fp32 VALU.
// Block = 64 rows x one class (4 chunks of 128 svs), waves 2x2, wave = 2x4
// tiles of mfma_f32_16x16x32_f16. T accumulated in regs, flushed once.

#define GAMMA 0.01f
constexpr int N  = 8192;
constexpr int D  = 256;
constexpr int S  = 5000;
constexpr int C  = 10;
constexpr int NV = 500;
constexpr int R  = 9;   // C-1

typedef _Float16 f16x8 __attribute__((ext_vector_type(8)));
typedef _Float16 f16x4 __attribute__((ext_vector_type(4)));
typedef float    f32x4 __attribute__((ext_vector_type(4)));

// ---------------- split planes: hi = f16(x), lo = f16((x-hi)*4096) ----------
__global__ __launch_bounds__(256) void prep_kernel(const float* __restrict__ x,
                                                   const float* __restrict__ sv,
                                                   _Float16* __restrict__ xh,
                                                   _Float16* __restrict__ xl,
                                                   _Float16* __restrict__ sh,
                                                   _Float16* __restrict__ sl) {
    const int XT = N * D / 4;
    const int ST = S * D / 4;
    int i = blockIdx.x * blockDim.x + threadIdx.x;
    if (i >= XT + ST) return;
    const float4* src;
    _Float16 *dh, *dl;
    int idx;
    if (i < XT) { src = (const float4*)x;  dh = xh; dl = sl /*dummy*/; dl = xl; idx = i; }
    else        { src = (const float4*)sv; dh = sh; dl = sl;           idx = i - XT; }
    float4 v = src[idx];
    f16x4 h, l;
    float vv[4] = {v.x, v.y, v.z, v.w};
#pragma unroll
    for (int k = 0; k < 4; ++k) {
        _Float16 hi = (_Float16)vv[k];
        h[k] = hi;
        l[k] = (_Float16)((vv[k] - (float)hi) * 4096.0f);
    }
    *(f16x4*)(dh + (size_t)idx * 4) = h;
    *(f16x4*)(dl + (size_t)idx * 4) = l;
}

// ---------------- norms: one wave per row (exact fp32) ----------------------
__global__ __launch_bounds__(256) void norm_kernel(const float* __restrict__ x,
                                                   const float* __restrict__ sv,
                                                   float* __restrict__ xn,
                                                   float* __restrict__ svn) {
    int gid  = blockIdx.x * blockDim.x + threadIdx.x;
    int wid  = gid >> 6;
    int lane = gid & 63;
    if (wid >= N + S) return;
    const float* row = (wid < N) ? (x + (size_t)wid * D) : (sv + (size_t)(wid - N) * D);
    float4 v = reinterpret_cast<const float4*>(row)[lane];
    float s = v.x * v.x + v.y * v.y + v.z * v.z + v.w * v.w;
#pragma unroll
    for (int off = 32; off > 0; off >>= 1) s += __shfl_xor(s, off, 64);
    if (lane == 0) {
        if (wid < N) xn[wid] = s;
        else         svn[wid - N] = s;
    }
}

// ---------------- fused split-MFMA GEMM + exp + weighted reduce -------------
// grid: (128 row tiles, 10 classes). block 256 = 4 waves (wm,wn in 2x2).
// wave tile: 32 rows x 64 cols = 2x4 mfma tiles (16x16x32).
__global__ __launch_bounds__(256, 2) void svc_gemm(const _Float16* __restrict__ xh,
                                                   const _Float16* __restrict__ xl,
                                                   const _Float16* __restrict__ sh,
                                                   const _Float16* __restrict__ sl,
                                                   const float* __restrict__ a,
                                                   const float* __restrict__ xnorm,
                                                   const float* __restrict__ svnorm,
                                                   float* __restrict__ T) {
    // LDS: XOR-swizzled [row][k] tiles, 16B slots, slot = (kgroup + row) & 3.
    __shared__ _Float16 As[2][64 * 32];    // plane 0 = hi, 1 = lo
    __shared__ _Float16 Bs[2][128 * 32];
    __shared__ float a_sh[R][512];
    __shared__ float sn_sh[512];
    __shared__ float tred[64 * R];

    const int tid  = threadIdx.x;
    const int n0   = blockIdx.x * 64;
    const int cls  = blockIdx.y;
    const int w    = tid >> 6;
    const int lane = tid & 63;
    const int wm   = w >> 1;               // 0..1: row half
    const int wn   = w & 1;                // 0..1: col half
    const int lx   = lane & 15;
    const int quad = lane >> 4;

    // stage class dual-coefs (zero-padded 500->512) + sv norms + zero tred
    for (int i = tid; i < R * 512; i += 256) {
        int r = i >> 9, cseg = i & 511;
        a_sh[r][cseg] = (cseg < NV) ? a[(size_t)r * S + cls * NV + cseg] : 0.0f;
    }
    for (int i = tid; i < 512; i += 256) {
        int svi = cls * NV + ((i < NV) ? i : NV - 1);
        sn_sh[i] = svnorm[svi];
    }
    for (int i = tid; i < 64 * R; i += 256) tred[i] = 0.0f;

    // per-lane x norms for this lane's 8 output rows
    float xnr[2][4];
#pragma unroll
    for (int ti = 0; ti < 2; ++ti)
#pragma unroll
        for (int reg = 0; reg < 4; ++reg)
            xnr[ti][reg] = xnorm[n0 + wm * 32 + ti * 16 + quad * 4 + reg];

    float tloc[8][R];
#pragma unroll
    for (int i = 0; i < 8; ++i)
#pragma unroll
        for (int r = 0; r < R; ++r) tloc[i][r] = 0.0f;

    // kb-invariant LDS fragment offsets (f16 units)
    int aoff[2], boff[4];
#pragma unroll
    for (int ti = 0; ti < 2; ++ti) {
        int row = wm * 32 + ti * 16 + lx;
        aoff[ti] = row * 32 + ((quad + row) & 3) * 8;
    }
#pragma unroll
    for (int tj = 0; tj < 4; ++tj) {
        int row = wn * 64 + tj * 16 + lx;
        boff[tj] = row * 32 + ((quad + row) & 3) * 8;
    }
    // staging destinations (kb-invariant)
    const int arow = tid >> 2, ag = tid & 3;
    const int adst = arow * 32 + ((ag + arow) & 3) * 8;
    const int brow0 = tid >> 2,          bg0 = tid & 3;
    const int brow1 = (tid + 256) >> 2,  bg1 = tid & 3;
    const int bdst0 = brow0 * 32 + ((bg0 + brow0) & 3) * 8;
    const int bdst1 = brow1 * 32 + ((bg1 + brow1) & 3) * 8;

    __syncthreads();

    const int segend = cls * NV + NV - 1;
    for (int ch = 0; ch < 4; ++ch) {
        f32x4 accM[2][4], accC[2][4];
#pragma unroll
        for (int ti = 0; ti < 2; ++ti)
#pragma unroll
            for (int tj = 0; tj < 4; ++tj) {
                accM[ti][tj] = (f32x4){0.f, 0.f, 0.f, 0.f};
                accC[ti][tj] = (f32x4){0.f, 0.f, 0.f, 0.f};
            }
        const int svbase = cls * NV + ch * 128;

        for (int kb = 0; kb < 8; ++kb) {
            __syncthreads();               // staging buffers free
            {   // stage A tile (hi + lo): 64 rows x 32 k
                size_t go = (size_t)(n0 + arow) * D + kb * 32 + ag * 8;
                *(f16x8*)(&As[0][adst]) = *(const f16x8*)(xh + go);
                *(f16x8*)(&As[1][adst]) = *(const f16x8*)(xl + go);
            }
            {   // stage B tile (hi + lo): 128 sv-rows x 32 k (clamped tail)
                int svr = svbase + brow0; if (svr > segend) svr = segend;
                size_t go = (size_t)svr * D + kb * 32 + bg0 * 8;
                *(f16x8*)(&Bs[0][bdst0]) = *(const f16x8*)(sh + go);
                *(f16x8*)(&Bs[1][bdst0]) = *(const f16x8*)(sl + go);
                svr = svbase + brow1; if (svr > segend) svr = segend;
                go = (size_t)svr * D + kb * 32 + bg1 * 8;
                *(f16x8*)(&Bs[0][bdst1]) = *(const f16x8*)(sh + go);
                *(f16x8*)(&Bs[1][bdst1]) = *(const f16x8*)(sl + go);
            }
            __syncthreads();

            f16x8 Af[2][2], Bf[2][4];
#pragma unroll
            for (int ti = 0; ti < 2; ++ti) {
                Af[0][ti] = *(const f16x8*)(&As[0][aoff[ti]]);
                Af[1][ti] = *(const f16x8*)(&As[1][aoff[ti]]);
            }
#pragma unroll
            for (int tj = 0; tj < 4; ++tj) {
                Bf[0][tj] = *(const f16x8*)(&Bs[0][boff[tj]]);
                Bf[1][tj] = *(const f16x8*)(&Bs[1][boff[tj]]);
            }
#pragma unroll
            for (int ti = 0; ti < 2; ++ti)
#pragma unroll
                for (int tj = 0; tj < 4; ++tj) {
                    accM[ti][tj] = __builtin_amdgcn_mfma_f32_16x16x32_f16(
                        Af[0][ti], Bf[0][tj], accM[ti][tj], 0, 0, 0);
                    accC[ti][tj] = __builtin_amdgcn_mfma_f32_16x16x32_f16(
                        Af[0][ti], Bf[1][tj], accC[ti][tj], 0, 0, 0);
                    accC[ti][tj] = __builtin_amdgcn_mfma_f32_16x16x32_f16(
                        Af[1][ti], Bf[0][tj], accC[ti][tj], 0, 0, 0);
                }
        }

        // epilogue: exp + 9-way weighted accumulate (VALU, co-issues with MFMA)
#pragma unroll
        for (int tj = 0; tj < 4; ++tj) {
            int cseg = ch * 128 + wn * 64 + tj * 16 + lx;
            float sn = sn_sh[cseg];
            float av[R];
#pragma unroll
            for (int r = 0; r < R; ++r) av[r] = a_sh[r][cseg];
#pragma unroll
            for (int ti = 0; ti < 2; ++ti)
#pragma unroll
                for (int reg = 0; reg < 4; ++reg) {
                    float dot = accM[ti][tj][reg]
                              + accC[ti][tj][reg] * (1.0f / 4096.0f);
                    float e  = fmaf(2.0f * GAMMA, dot, -GAMMA * (xnr[ti][reg] + sn));
                    float kv = __expf(e);
#pragma unroll
                    for (int r = 0; r < R; ++r)
                        tloc[ti * 4 + reg][r] = fmaf(av[r], kv, tloc[ti * 4 + reg][r]);
                }
        }
    }

    // flush: butterfly-sum the 16 lanes sharing each row, then 2 ds-atomics/row
#pragma unroll
    for (int i = 0; i < 8; ++i)
#pragma unroll
        for (int r = 0; r < R; ++r) {
            float v = tloc[i][r];
            v += __shfl_xor(v, 1, 64);
            v += __shfl_xor(v, 2, 64);
            v += __shfl_xor(v, 4, 64);
            v += __shfl_xor(v, 8, 64);
            tloc[i][r] = v;
        }
    if (lx == 0) {
#pragma unroll
        for (int i = 0; i < 8; ++i) {
            int ti = i >> 2, reg = i & 3;
            int row = wm * 32 + ti * 16 + quad * 4 + reg;
#pragma unroll
            for (int r = 0; r < R; ++r)
                atomicAdd(&tred[row * R + r], tloc[i][r]);
        }
    }
    __syncthreads();
    for (int i = tid; i < 64 * R; i += 256) {
        int row = i / R, r = i - row * R;
        T[(size_t)(n0 + row) * 90 + r * 10 + cls] = tred[i];
    }
}

// ---------------- pairwise voting + argmax ----------------------------------
__global__ __launch_bounds__(256) void vote_kernel(const float* __restrict__ T,
                                                   const float* __restrict__ b,
                                                   int* __restrict__ out) {
    int n = blockIdx.x * blockDim.x + threadIdx.x;
    if (n >= N) return;
    const float* Tn = T + (size_t)n * 90;
    float tv[90];
#pragma unroll
    for (int i = 0; i < 90; ++i) tv[i] = Tn[i];
    int counts[C];
#pragma unroll
    for (int k = 0; k < C; ++k) counts[k] = 0;
    int p = 0;
#pragma unroll
    for (int i = 0; i < C; ++i) {
#pragma unroll
        for (int j = i + 1; j < C; ++j) {
            float c = tv[i * 10 + j] + tv[(j - 1) * 10 + i] + b[p];
            if (c > 0.f) counts[i]++; else counts[j]++;
            ++p;
        }
    }
    int best = 0;
#pragma unroll
    for (int k = 1; k < C; ++k)
        if (counts[k] > counts[best]) best = k;
    out[n]     = best;
    out[N + n] = best;
}

extern "C" void kernel_launch(void* const* d_in, const int* in_sizes, int n_in,
                              void* d_out, int out_size, void* d_ws, size_t ws_size,
                              hipStream_t stream) {
    const float* x  = (const float*)d_in[0];   // [8192,256]
    const float* sv = (const float*)d_in[1];   // [5000,256]
    const float* a  = (const float*)d_in[2];   // [9,5000]
    const float* b  = (const float*)d_in[3];   // [45]
    int* out = (int*)d_out;

    // workspace: xh|xl (4MB ea) sh|sl (2.56MB ea) xnorm svnorm T  (~16.1 MB)
    char* wp = (char*)d_ws;
    _Float16* xh = (_Float16*)wp;  wp += (size_t)N * D * 2;
    _Float16* xl = (_Float16*)wp;  wp += (size_t)N * D * 2;
    _Float16* sh = (_Float16*)wp;  wp += (size_t)S * D * 2;
    _Float16* sl = (_Float16*)wp;  wp += (size_t)S * D * 2;
    float* xnorm  = (float*)wp;    wp += (size_t)N * 4;
    float* svnorm = (float*)wp;    wp += (size_t)S * 4;
    float* T      = (float*)wp;

    {   // split planes
        int total = (N * D + S * D) / 4;
        prep_kernel<<<(total + 255) / 256, 256, 0, stream>>>(x, sv, xh, xl, sh, sl);
    }
    {   // norms
        int waves = N + S;
        norm_kernel<<<(waves * 64 + 255) / 256, 256, 0, stream>>>(x, sv, xnorm, svnorm);
    }
    {   // fused GEMM
        dim3 grid(N / 64, C);
        svc_gemm<<<grid, 256, 0, stream>>>(xh, xl, sh, sl, a, xnorm, svnorm, T);
    }
    {   // voting
        vote_kernel<<<N / 256, 256, 0, stream>>>(T, b, out);
    }
}

// Round 3
// 204.660 us; speedup vs baseline: 2.5477x; 1.0290x over previous
//
#include <hip/hip_runtime.h>
#include <hip/hip_fp16.h>
#include <cmath>

// SVC_63737314673237 round 3: pipelined split-f16 MFMA GEMM.
// Same verified math/layout as R2 (dot = xh.sh + 2^-12*(xh.sl' + xl'.sh)),
// restructured K-loop: double-buffered LDS, ONE barrier per kb, register
// prefetch of kb+1 global loads hidden under kb's 24 MFMAs. prep+norm fused.

#define GAMMA 0.01f
constexpr int N  = 8192;
constexpr int D  = 256;
constexpr int S  = 5000;
constexpr int C  = 10;
constexpr int NV = 500;
constexpr int R  = 9;   // C-1

typedef _Float16 f16x8 __attribute__((ext_vector_type(8)));
typedef _Float16 f16x4 __attribute__((ext_vector_type(4)));
typedef float    f32x4 __attribute__((ext_vector_type(4)));

// ---------------- fused split + norms: one wave per row ---------------------
__global__ __launch_bounds__(256) void prep_kernel(const float* __restrict__ x,
                                                   const float* __restrict__ sv,
                                                   _Float16* __restrict__ xh,
                                                   _Float16* __restrict__ xl,
                                                   _Float16* __restrict__ sh,
                                                   _Float16* __restrict__ sl,
                                                   float* __restrict__ xn,
                                                   float* __restrict__ svn) {
    int gid  = blockIdx.x * blockDim.x + threadIdx.x;
    int wid  = gid >> 6;
    int lane = gid & 63;
    if (wid >= N + S) return;
    bool isx = wid < N;
    int  r   = isx ? wid : wid - N;
    const float* row = isx ? (x + (size_t)r * D) : (sv + (size_t)r * D);
    float4 v = reinterpret_cast<const float4*>(row)[lane];
    float s = v.x * v.x + v.y * v.y + v.z * v.z + v.w * v.w;
#pragma unroll
    for (int off = 32; off > 0; off >>= 1) s += __shfl_xor(s, off, 64);
    float vv[4] = {v.x, v.y, v.z, v.w};
    f16x4 h, l;
#pragma unroll
    for (int k = 0; k < 4; ++k) {
        _Float16 hi = (_Float16)vv[k];
        h[k] = hi;
        l[k] = (_Float16)((vv[k] - (float)hi) * 4096.0f);
    }
    size_t o = (size_t)r * D + lane * 4;
    *(f16x4*)((isx ? xh : sh) + o) = h;
    *(f16x4*)((isx ? xl : sl) + o) = l;
    if (lane == 0) (isx ? xn : svn)[r] = s;
}

// ---------------- pipelined split-MFMA GEMM + exp + weighted reduce ---------
// grid: (128 row tiles, 10 classes). block 256 = 4 waves (wm,wn in 2x2).
// wave tile: 32 rows x 64 cols = 2x4 mfma tiles (16x16x32).
// 32 phases = 4 sv-chunks x 8 kb; LDS double-buffered, 1 barrier/phase.
__global__ __launch_bounds__(256, 2) void svc_gemm(const _Float16* __restrict__ xh,
                                                   const _Float16* __restrict__ xl,
                                                   const _Float16* __restrict__ sh,
                                                   const _Float16* __restrict__ sl,
                                                   const float* __restrict__ a,
                                                   const float* __restrict__ xnorm,
                                                   const float* __restrict__ svnorm,
                                                   float* __restrict__ T) {
    __shared__ _Float16 As[2][2][64 * 32];   // [buf][plane]
    __shared__ _Float16 Bs[2][2][128 * 32];
    __shared__ float a_sh[R][512];
    __shared__ float sn_sh[512];
    __shared__ float tred[64 * R];

    const int tid  = threadIdx.x;
    const int n0   = blockIdx.x * 64;
    const int cls  = blockIdx.y;
    const int w    = tid >> 6;
    const int lane = tid & 63;
    const int wm   = w >> 1;
    const int wn   = w & 1;
    const int lx   = lane & 15;
    const int quad = lane >> 4;

    for (int i = tid; i < R * 512; i += 256) {
        int r = i >> 9, cseg = i & 511;
        a_sh[r][cseg] = (cseg < NV) ? a[(size_t)r * S + cls * NV + cseg] : 0.0f;
    }
    for (int i = tid; i < 512; i += 256) {
        int svi = cls * NV + ((i < NV) ? i : NV - 1);
        sn_sh[i] = svnorm[svi];
    }
    for (int i = tid; i < 64 * R; i += 256) tred[i] = 0.0f;

    float xnr[2][4];
#pragma unroll
    for (int ti = 0; ti < 2; ++ti)
#pragma unroll
        for (int reg = 0; reg < 4; ++reg)
            xnr[ti][reg] = xnorm[n0 + wm * 32 + ti * 16 + quad * 4 + reg];

    float tloc[8][R];
#pragma unroll
    for (int i = 0; i < 8; ++i)
#pragma unroll
        for (int r = 0; r < R; ++r) tloc[i][r] = 0.0f;

    // fragment offsets (f16 units), XOR-swizzled 16B slots
    int aoff[2], boff[4];
#pragma unroll
    for (int ti = 0; ti < 2; ++ti) {
        int row = wm * 32 + ti * 16 + lx;
        aoff[ti] = row * 32 + ((quad + row) & 3) * 8;
    }
#pragma unroll
    for (int tj = 0; tj < 4; ++tj) {
        int row = wn * 64 + tj * 16 + lx;
        boff[tj] = row * 32 + ((quad + row) & 3) * 8;
    }
    const int arow = tid >> 2, ag = tid & 3;
    const int adst = arow * 32 + ((ag + arow) & 3) * 8;
    const int brow0 = tid >> 2, brow1 = (tid >> 2) + 64;
    const int bdst0 = brow0 * 32 + ((ag + brow0) & 3) * 8;
    const int bdst1 = brow1 * 32 + ((ag + brow1) & 3) * 8;
    const int segend = cls * NV + NV - 1;

    f32x4 accM[2][4], accC[2][4];
#pragma unroll
    for (int ti = 0; ti < 2; ++ti)
#pragma unroll
        for (int tj = 0; tj < 4; ++tj) {
            accM[ti][tj] = (f32x4){0.f, 0.f, 0.f, 0.f};
            accC[ti][tj] = (f32x4){0.f, 0.f, 0.f, 0.f};
        }

    // prefetch registers
    f16x8 pAh, pAl, pBh0, pBl0, pBh1, pBl1;
    auto load_phase = [&](int ph) {
        int ch = ph >> 3, kb = ph & 7;
        size_t goA = (size_t)(n0 + arow) * D + kb * 32 + ag * 8;
        pAh = *(const f16x8*)(xh + goA);
        pAl = *(const f16x8*)(xl + goA);
        int svbase = cls * NV + ch * 128;
        int svr = svbase + brow0; if (svr > segend) svr = segend;
        size_t go = (size_t)svr * D + kb * 32 + ag * 8;
        pBh0 = *(const f16x8*)(sh + go);
        pBl0 = *(const f16x8*)(sl + go);
        svr = svbase + brow1; if (svr > segend) svr = segend;
        go = (size_t)svr * D + kb * 32 + ag * 8;
        pBh1 = *(const f16x8*)(sh + go);
        pBl1 = *(const f16x8*)(sl + go);
    };
    auto store_phase = [&](int buf) {
        *(f16x8*)(&As[buf][0][adst])  = pAh;
        *(f16x8*)(&As[buf][1][adst])  = pAl;
        *(f16x8*)(&Bs[buf][0][bdst0]) = pBh0;
        *(f16x8*)(&Bs[buf][1][bdst0]) = pBl0;
        *(f16x8*)(&Bs[buf][0][bdst1]) = pBh1;
        *(f16x8*)(&Bs[buf][1][bdst1]) = pBl1;
    };

    load_phase(0);
    store_phase(0);
    __syncthreads();

    for (int ph = 0; ph < 32; ++ph) {
        const int buf = ph & 1;
        if (ph < 31) load_phase(ph + 1);   // global loads overlap MFMAs below

        f16x8 Af[2][2], Bf[2][4];
#pragma unroll
        for (int ti = 0; ti < 2; ++ti) {
            Af[0][ti] = *(const f16x8*)(&As[buf][0][aoff[ti]]);
            Af[1][ti] = *(const f16x8*)(&As[buf][1][aoff[ti]]);
        }
#pragma unroll
        for (int tj = 0; tj < 4; ++tj) {
            Bf[0][tj] = *(const f16x8*)(&Bs[buf][0][boff[tj]]);
            Bf[1][tj] = *(const f16x8*)(&Bs[buf][1][boff[tj]]);
        }
#pragma unroll
        for (int ti = 0; ti < 2; ++ti)
#pragma unroll
            for (int tj = 0; tj < 4; ++tj) {
                accM[ti][tj] = __builtin_amdgcn_mfma_f32_16x16x32_f16(
                    Af[0][ti], Bf[0][tj], accM[ti][tj], 0, 0, 0);
                accC[ti][tj] = __builtin_amdgcn_mfma_f32_16x16x32_f16(
                    Af[0][ti], Bf[1][tj], accC[ti][tj], 0, 0, 0);
                accC[ti][tj] = __builtin_amdgcn_mfma_f32_16x16x32_f16(
                    Af[1][ti], Bf[0][tj], accC[ti][tj], 0, 0, 0);
            }

        if (ph < 31) store_phase(buf ^ 1); // waits prefetch; other buffer
        __syncthreads();

        if ((ph & 7) == 7) {               // chunk complete: epilogue (VALU)
            const int ch = ph >> 3;
#pragma unroll
            for (int tj = 0; tj < 4; ++tj) {
                int cseg = ch * 128 + wn * 64 + tj * 16 + lx;
                float sn = sn_sh[cseg];
                float av[R];
#pragma unroll
                for (int r = 0; r < R; ++r) av[r] = a_sh[r][cseg];
#pragma unroll
                for (int ti = 0; ti < 2; ++ti)
#pragma unroll
                    for (int reg = 0; reg < 4; ++reg) {
                        float dot = accM[ti][tj][reg]
                                  + accC[ti][tj][reg] * (1.0f / 4096.0f);
                        float e  = fmaf(2.0f * GAMMA, dot,
                                        -GAMMA * (xnr[ti][reg] + sn));
                        float kv = __expf(e);
#pragma unroll
                        for (int r = 0; r < R; ++r)
                            tloc[ti * 4 + reg][r] =
                                fmaf(av[r], kv, tloc[ti * 4 + reg][r]);
                    }
            }
#pragma unroll
            for (int ti = 0; ti < 2; ++ti)
#pragma unroll
                for (int tj = 0; tj < 4; ++tj) {
                    accM[ti][tj] = (f32x4){0.f, 0.f, 0.f, 0.f};
                    accC[ti][tj] = (f32x4){0.f, 0.f, 0.f, 0.f};
                }
        }
    }

    // butterfly-sum the 16 lanes sharing each row, then 2 ds-atomics/row
#pragma unroll
    for (int i = 0; i < 8; ++i)
#pragma unroll
        for (int r = 0; r < R; ++r) {
            float v = tloc[i][r];
            v += __shfl_xor(v, 1, 64);
            v += __shfl_xor(v, 2, 64);
            v += __shfl_xor(v, 4, 64);
            v += __shfl_xor(v, 8, 64);
            tloc[i][r] = v;
        }
    if (lx == 0) {
#pragma unroll
        for (int i = 0; i < 8; ++i) {
            int ti = i >> 2, reg = i & 3;
            int row = wm * 32 + ti * 16 + quad * 4 + reg;
#pragma unroll
            for (int r = 0; r < R; ++r)
                atomicAdd(&tred[row * R + r], tloc[i][r]);
        }
    }
    __syncthreads();
    for (int i = tid; i < 64 * R; i += 256) {
        int row = i / R, r = i - row * R;
        T[(size_t)(n0 + row) * 90 + r * 10 + cls] = tred[i];
    }
}

// ---------------- pairwise voting + argmax ----------------------------------
__global__ __launch_bounds__(256) void vote_kernel(const float* __restrict__ T,
                                                   const float* __restrict__ b,
                                                   int* __restrict__ out) {
    int n = blockIdx.x * blockDim.x + threadIdx.x;
    if (n >= N) return;
    const float* Tn = T + (size_t)n * 90;
    float tv[90];
#pragma unroll
    for (int i = 0; i < 90; ++i) tv[i] = Tn[i];
    int counts[C];
#pragma unroll
    for (int k = 0; k < C; ++k) counts[k] = 0;
    int p = 0;
#pragma unroll
    for (int i = 0; i < C; ++i) {
#pragma unroll
        for (int j = i + 1; j < C; ++j) {
            float c = tv[i * 10 + j] + tv[(j - 1) * 10 + i] + b[p];
            if (c > 0.f) counts[i]++; else counts[j]++;
            ++p;
        }
    }
    int best = 0;
#pragma unroll
    for (int k = 1; k < C; ++k)
        if (counts[k] > counts[best]) best = k;
    out[n]     = best;
    out[N + n] = best;
}

extern "C" void kernel_launch(void* const* d_in, const int* in_sizes, int n_in,
                              void* d_out, int out_size, void* d_ws, size_t ws_size,
                              hipStream_t stream) {
    const float* x  = (const float*)d_in[0];   // [8192,256]
    const float* sv = (const float*)d_in[1];   // [5000,256]
    const float* a  = (const float*)d_in[2];   // [9,5000]
    const float* b  = (const float*)d_in[3];   // [45]
    int* out = (int*)d_out;

    char* wp = (char*)d_ws;
    _Float16* xh = (_Float16*)wp;  wp += (size_t)N * D * 2;
    _Float16* xl = (_Float16*)wp;  wp += (size_t)N * D * 2;
    _Float16* sh = (_Float16*)wp;  wp += (size_t)S * D * 2;
    _Float16* sl = (_Float16*)wp;  wp += (size_t)S * D * 2;
    float* xnorm  = (float*)wp;    wp += (size_t)N * 4;
    float* svnorm = (float*)wp;    wp += (size_t)S * 4;
    float* T      = (float*)wp;

    {   // fused split + norms: one wave per row
        int waves = N + S;
        prep_kernel<<<(waves * 64 + 255) / 256, 256, 0, stream>>>(
            x, sv, xh, xl, sh, sl, xnorm, svnorm);
    }
    {   // pipelined GEMM
        dim3 grid(N / 64, C);
        svc_gemm<<<grid, 256, 0, stream>>>(xh, xl, sh, sl, a, xnorm, svnorm, T);
    }
    {   // voting
        vote_kernel<<<N / 256, 256, 0, stream>>>(T, b, out);
    }
}